// Round 7
// baseline (1283.894 us; speedup 1.0000x reference)
//
#include <hip/hip_runtime.h>

#define N_NODES_C 100000
#define N_REL_C 5
#define N_TOT (N_REL_C * N_NODES_C)
#define FEAT 128
#define KTOT 768        // virtual K = 128 (root) + 5*128 (relations)
#define BM 128          // rows per block

typedef __attribute__((ext_vector_type(8))) short bf16x8;
typedef __attribute__((ext_vector_type(4))) float f32x4;

__device__ inline unsigned short f2bf(float f) {
    union { float f; unsigned int u; } v; v.f = f;
    return (unsigned short)((v.u + 0x7FFFu + ((v.u >> 16) & 1u)) >> 16);
}

// async 16B global->LDS: lds dest = wave-uniform base + lane*16 (m97 pattern)
__device__ __forceinline__ void g2l16(const void* g, void* l) {
    __builtin_amdgcn_global_load_lds((const __attribute__((address_space(1))) unsigned int*)g,
                                     (__attribute__((address_space(3))) unsigned int*)l,
                                     16, 0, 0);
}

// ---------------------------------------------------------------------------
// preprocessing: counts, inv, scan -> CSR grouped by (relation, dst)
// ---------------------------------------------------------------------------
__global__ __launch_bounds__(256) void count_edges(const int* __restrict__ dst,
                                                   const int* __restrict__ et,
                                                   int* __restrict__ cnt, int E) {
    int e = blockIdx.x * 256 + threadIdx.x;
    if (e < E) atomicAdd(&cnt[et[e] * N_NODES_C + dst[e]], 1);
}

__global__ __launch_bounds__(256) void make_inv(const int* __restrict__ cnt,
                                                float* __restrict__ inv, int n) {
    int i = blockIdx.x * 256 + threadIdx.x;
    if (i < n) inv[i] = 1.0f / (float)(cnt[i] > 1 ? cnt[i] : 1);
}

__global__ __launch_bounds__(256) void scan_block(const int* __restrict__ cnt,
                                                  int* __restrict__ rowptr,
                                                  int* __restrict__ bsum, int n) {
    __shared__ int sh[256];
    int tid = threadIdx.x;
    int i = blockIdx.x * 256 + tid;
    int v = (i < n) ? cnt[i] : 0;
    sh[tid] = v;
    __syncthreads();
#pragma unroll
    for (int o = 1; o < 256; o <<= 1) {
        int t = (tid >= o) ? sh[tid - o] : 0;
        __syncthreads();
        sh[tid] += t;
        __syncthreads();
    }
    if (i < n) rowptr[i] = sh[tid] - v;
    if (tid == 255) bsum[blockIdx.x] = sh[255];
}

__global__ __launch_bounds__(256) void scan_bsum(int* __restrict__ bsum, int nb) {
    __shared__ int sh[256];
    __shared__ int carry;
    int tid = threadIdx.x;
    if (tid == 0) carry = 0;
    __syncthreads();
    for (int base = 0; base < nb; base += 256) {
        int i = base + tid;
        int v = (i < nb) ? bsum[i] : 0;
        sh[tid] = v;
        __syncthreads();
#pragma unroll
        for (int o = 1; o < 256; o <<= 1) {
            int t = (tid >= o) ? sh[tid - o] : 0;
            __syncthreads();
            sh[tid] += t;
            __syncthreads();
        }
        int excl = sh[tid] - v + carry;
        int chunk_total = sh[255];
        __syncthreads();
        if (i < nb) bsum[i] = excl;
        if (tid == 0) carry += chunk_total;
        __syncthreads();
    }
}

__global__ __launch_bounds__(256) void scan_add(int* __restrict__ rowptr,
                                                const int* __restrict__ bsum,
                                                int n, int Etot) {
    int i = blockIdx.x * 256 + threadIdx.x;
    if (i < n) rowptr[i] += bsum[blockIdx.x];
    if (i == 0) rowptr[n] = Etot;
}

__global__ __launch_bounds__(256) void fill_csr(const int* __restrict__ src,
                                                const int* __restrict__ dst,
                                                const int* __restrict__ et,
                                                int* __restrict__ cursor,
                                                int* __restrict__ esrc, int E) {
    int e = blockIdx.x * 256 + threadIdx.x;
    if (e < E) {
        int pos = atomicAdd(&cursor[et[e] * N_NODES_C + dst[e]], 1);
        esrc[pos] = src[e];
    }
}

// ---------------------------------------------------------------------------
// conversions to bf16
// ---------------------------------------------------------------------------
__global__ __launch_bounds__(256) void convert_x(const float* __restrict__ x,
                                                 unsigned short* __restrict__ xb, int n4) {
    int i = blockIdx.x * 256 + threadIdx.x;
    if (i >= n4) return;
    float4 v = ((const float4*)x)[i];
    ushort4 o;
    o.x = f2bf(v.x); o.y = f2bf(v.y); o.z = f2bf(v.z); o.w = f2bf(v.w);
    ((ushort4*)xb)[i] = o;
}

// Bt[c][kv] (col-major over virtual K): kv<128 -> root[kv][c]; else W[r][kk][c]
__global__ __launch_bounds__(256) void convert_w(const float* __restrict__ root,
                                                 const float* __restrict__ W,
                                                 unsigned short* __restrict__ Bt) {
    int idx = blockIdx.x * 256 + threadIdx.x;
    if (idx >= FEAT * KTOT) return;
    int c = idx / KTOT;
    int kv = idx - c * KTOT;
    float val;
    if (kv < FEAT) {
        val = root[kv * FEAT + c];
    } else {
        int r = (kv - FEAT) >> 7;
        int kk = (kv - FEAT) & 127;
        val = W[((size_t)r * FEAT + kk) * FEAT + c];
    }
    Bt[idx] = f2bf(val);
}

// ---------------------------------------------------------------------------
// fused layer: out[n][:] = relu( hb[n][:]@root + sum_r mean_r(hb)[n][:]@W_r + b )
// Block = 128 nodes. Phase 0: As <- hb rows (g2l16) + MFMA vs root.
// Phase 1..5: As <- gather-mean of relation r (direct LDS stores, quarter-wave
// per node) + MFMA vs W_r (Bs staged in 64-K halves -> 48 KB LDS, 3 blocks/CU).
// LDS chunk-XOR swizzle on low-3 chunk bits (2-way bank aliasing = free, m136).
// ---------------------------------------------------------------------------
__global__ __launch_bounds__(256, 3) void rgcn_fused(
    const unsigned short* __restrict__ hb,
    const unsigned short* __restrict__ Bt,
    const float* __restrict__ bias,
    const int* __restrict__ esrc,
    const int* __restrict__ rowptr,
    const float* __restrict__ inv,
    float* __restrict__ outf,
    unsigned short* __restrict__ outb) {
    __shared__ unsigned short As[BM * FEAT];     // 32 KB, 16 chunks/row
    __shared__ unsigned short Bs[FEAT * 64];     // 16 KB, 8 chunks/col (half-K)

    const int tid = threadIdx.x;
    const int w = tid >> 6, lane = tid & 63;
    const int wr = w >> 1, wc = w & 1;
    const int lm = lane & 15, lq = lane >> 4;
    const int qw = tid >> 4, seg = tid & 15;
    const int brow0 = blockIdx.x * BM;

    f32x4 acc[4][4];
#pragma unroll
    for (int i = 0; i < 4; i++)
#pragma unroll
        for (int j = 0; j < 4; j++) acc[i][j] = (f32x4){0.f, 0.f, 0.f, 0.f};

    // A root staging: 2048 chunks (128 rows x 16), 8 instr/wave
    size_t asrc[8]; int aldsbase[8];
#pragma unroll
    for (int i = 0; i < 8; i++) {
        int cid = (w * 8 + i) * 64 + lane;
        int row = cid >> 4, c = cid & 15;
        int cs = (c & 8) | ((c ^ (row & 7)) & 7);
        int gr = brow0 + row;
        if (gr >= N_NODES_C) gr = N_NODES_C - 1;
        asrc[i] = ((size_t)gr << 7) + cs * 8;
        aldsbase[i] = (w * 8 + i) * 64 * 8;
    }
    // B staging: 1024 chunks per half (128 cols x 8), 4 instr/wave
    size_t bsrc[4]; int bldsbase[4];
#pragma unroll
    for (int i = 0; i < 4; i++) {
        int cid = (w * 4 + i) * 64 + lane;
        int col = cid >> 3, c = cid & 7;
        int cs = c ^ (col & 7);
        bsrc[i] = (size_t)col * KTOT + cs * 8;
        bldsbase[i] = (w * 4 + i) * 64 * 8;
    }

    for (int ph = 0; ph < 6; ph++) {
        const int kv0 = ph * FEAT;
        __syncthreads();   // prev MFMA reads of As/Bs done
        // Bs half 0 (async)
#pragma unroll
        for (int i = 0; i < 4; i++)
            g2l16(Bt + bsrc[i] + kv0, &Bs[bldsbase[i]]);
        if (ph == 0) {
#pragma unroll
            for (int i = 0; i < 8; i++)
                g2l16(hb + asrc[i], &As[aldsbase[i]]);
        } else {
            const int r = ph - 1;
            // gather-mean: quarter-wave per node, 8 nodes each
            for (int n = 0; n < 8; n++) {
                int idx = n * 16 + qw;
                int node = brow0 + idx;
                float a[8] = {0.f, 0.f, 0.f, 0.f, 0.f, 0.f, 0.f, 0.f};
                float sc = 0.f;
                if (node < N_NODES_C) {
                    int base = r * N_NODES_C + node;
                    int lo = rowptr[base], hi = rowptr[base + 1];
                    for (int e = lo; e < hi; e++) {
                        int s = esrc[e];
                        uint4 u = *(const uint4*)(hb + ((size_t)s << 7) + seg * 8);
                        union { unsigned int u; float f; } t;
                        t.u = u.x << 16;         a[0] += t.f;
                        t.u = u.x & 0xFFFF0000u; a[1] += t.f;
                        t.u = u.y << 16;         a[2] += t.f;
                        t.u = u.y & 0xFFFF0000u; a[3] += t.f;
                        t.u = u.z << 16;         a[4] += t.f;
                        t.u = u.z & 0xFFFF0000u; a[5] += t.f;
                        t.u = u.w << 16;         a[6] += t.f;
                        t.u = u.w & 0xFFFF0000u; a[7] += t.f;
                    }
                    sc = inv[base];
                }
                uint4 o;
                o.x = ((unsigned int)f2bf(a[1] * sc) << 16) | f2bf(a[0] * sc);
                o.y = ((unsigned int)f2bf(a[3] * sc) << 16) | f2bf(a[2] * sc);
                o.z = ((unsigned int)f2bf(a[5] * sc) << 16) | f2bf(a[4] * sc);
                o.w = ((unsigned int)f2bf(a[7] * sc) << 16) | f2bf(a[6] * sc);
                int cs = (seg & 8) | ((seg ^ (idx & 7)) & 7);
                *(uint4*)&As[idx * FEAT + cs * 8] = o;
            }
        }
        __syncthreads();   // As complete + Bs half0 (vmcnt drained at barrier)

#pragma unroll
        for (int hh = 0; hh < 4; hh++) {
            if (hh == 2) {
                __syncthreads();   // half0 reads done
#pragma unroll
                for (int i = 0; i < 4; i++)
                    g2l16(Bt + bsrc[i] + kv0 + 64, &Bs[bldsbase[i]]);
                __syncthreads();   // half1 staged
            }
            bf16x8 af[4], bf[4];
#pragma unroll
            for (int t = 0; t < 4; t++) {
                int row = wr * 64 + t * 16 + lm;
                int ch = hh * 4 + lq;
                int ca = (ch & 8) | ((ch ^ (row & 7)) & 7);
                af[t] = *(const bf16x8*)&As[row * FEAT + ca * 8];
                int col = wc * 64 + t * 16 + lm;
                int cb = ((hh & 1) * 4 + lq) ^ (col & 7);
                bf[t] = *(const bf16x8*)&Bs[col * 64 + cb * 8];
            }
#pragma unroll
            for (int i = 0; i < 4; i++)
#pragma unroll
                for (int j = 0; j < 4; j++)
                    acc[i][j] = __builtin_amdgcn_mfma_f32_16x16x32_bf16(af[i], bf[j], acc[i][j], 0, 0, 0);
        }
    }

    float bcol[4];
#pragma unroll
    for (int j = 0; j < 4; j++) bcol[j] = bias[wc * 64 + j * 16 + lm];

#pragma unroll
    for (int i = 0; i < 4; i++) {
#pragma unroll
        for (int reg = 0; reg < 4; reg++) {
            int lr = brow0 + wr * 64 + i * 16 + lq * 4 + reg;
            if (lr < N_NODES_C) {
                size_t grow = (size_t)lr << 7;
#pragma unroll
                for (int j = 0; j < 4; j++) {
                    float v = acc[i][j][reg] + bcol[j];
                    v = fmaxf(v, 0.f);
                    int col = wc * 64 + j * 16 + lm;
                    if (outf) outf[grow + col] = v;
                    else outb[grow + col] = f2bf(v);
                }
            }
        }
    }
}

// ---------------------------------------------------------------------------
extern "C" void kernel_launch(void* const* d_in, const int* in_sizes, int n_in,
                              void* d_out, int out_size, void* d_ws, size_t ws_size,
                              hipStream_t stream) {
    const float* x = (const float*)d_in[0];
    const int* ei  = (const int*)d_in[1];
    const int* et  = (const int*)d_in[2];
    const int E = in_sizes[2];
    const int* src  = ei;
    const int* dstp = ei + E;

    // workspace layout (~71.4 MB total; 119.4 MB proven safe in round 2):
    //   inv    @ 0           (2,000,000)
    //   rowptr @ 2,097,152   (2,000,004)
    //   esrc   @ 4,194,304   (6,400,000)
    //   xbA    @ 10,616,832  (25,600,000)
    //   xbB    @ 36,306,944  (25,600,000)
    //   Bt     @ 61,997,056  (589,824)
    //   cnt    @ 67,108,864  (2,000,000)
    //   cursor @ 69,206,016  (2,000,000)
    //   bsum   @ 71,303,168  (~8 KB)
    char* ws = (char*)d_ws;
    float* inv             = (float*)ws;
    int*   rowptr          = (int*)(ws + 2097152);
    int*   esrc            = (int*)(ws + 4194304);
    unsigned short* xbA    = (unsigned short*)(ws + 10616832);
    unsigned short* xbB    = (unsigned short*)(ws + 36306944);
    unsigned short* BtAll  = (unsigned short*)(ws + 61997056);
    int*   cnt    = (int*)(ws + 67108864);
    int*   cursor = (int*)(ws + 69206016);
    int*   bsum   = (int*)(ws + 71303168);

    const int nscan_blocks = (N_TOT + 255) / 256;

    hipMemsetAsync(cnt, 0, (size_t)N_TOT * 4, stream);
    count_edges<<<(E + 255) / 256, 256, 0, stream>>>(dstp, et, cnt, E);
    make_inv<<<(N_TOT + 255) / 256, 256, 0, stream>>>(cnt, inv, N_TOT);
    scan_block<<<nscan_blocks, 256, 0, stream>>>(cnt, rowptr, bsum, N_TOT);
    scan_bsum<<<1, 256, 0, stream>>>(bsum, nscan_blocks);
    scan_add<<<nscan_blocks, 256, 0, stream>>>(rowptr, bsum, N_TOT, E);
    hipMemcpyAsync(cursor, rowptr, (size_t)N_TOT * 4, hipMemcpyDeviceToDevice, stream);
    fill_csr<<<(E + 255) / 256, 256, 0, stream>>>(src, dstp, et, cursor, esrc, E);

    const int n4 = N_NODES_C * FEAT / 4;
    convert_x<<<(n4 + 255) / 256, 256, 0, stream>>>(x, xbA, n4);

    const float* Wp[3] = {(const float*)d_in[3], (const float*)d_in[6], (const float*)d_in[9]};
    const float* Rp[3] = {(const float*)d_in[4], (const float*)d_in[7], (const float*)d_in[10]};
    const float* Bp[3] = {(const float*)d_in[5], (const float*)d_in[8], (const float*)d_in[11]};

    const int nw = FEAT * KTOT;
    for (int l = 0; l < 3; l++)
        convert_w<<<(nw + 255) / 256, 256, 0, stream>>>(Rp[l], Wp[l],
                                                        BtAll + (size_t)l * nw);

    const int fgrid = (N_NODES_C + BM - 1) / BM;   // 782

    // layer dataflow (bf16 ping-pong): xbA -> xbB -> xbA -> d_out(fp32)
    for (int l = 0; l < 3; l++) {
        const unsigned short* hin = (l == 1) ? xbB : xbA;
        unsigned short* outb = (l == 0) ? xbB : ((l == 1) ? xbA : nullptr);
        float* outf = (l == 2) ? (float*)d_out : nullptr;
        rgcn_fused<<<fgrid, 256, 0, stream>>>(hin, BtAll + (size_t)l * nw, Bp[l],
                                              esrc, rowptr, inv, outf, outb);
    }
}

// Round 9
// 868.335 us; speedup vs baseline: 1.4786x; 1.4786x over previous
//
#include <hip/hip_runtime.h>

#define N_NODES_C 100000
#define N_REL_C 5
#define N_TOT (N_REL_C * N_NODES_C)
#define FEAT 128
#define KTOT 768        // virtual K = 128 (root) + 5*128 (relations)
#define BM 128          // GEMM block rows
#define GBK 64          // GEMM K-tile
#define NBUK 64         // dst buckets (dst>>11), 49 used

typedef __attribute__((ext_vector_type(8))) short bf16x8;
typedef __attribute__((ext_vector_type(4))) float f32x4;
typedef __attribute__((ext_vector_type(4))) unsigned int u32x4;

__device__ inline unsigned short f2bf(float f) {
    union { float f; unsigned int u; } v; v.f = f;
    return (unsigned short)((v.u + 0x7FFFu + ((v.u >> 16) & 1u)) >> 16);
}

// async 16B global->LDS: lds dest = wave-uniform base + lane*16 (m97 pattern)
__device__ __forceinline__ void g2l16(const void* g, void* l) {
    __builtin_amdgcn_global_load_lds((const __attribute__((address_space(1))) unsigned int*)g,
                                     (__attribute__((address_space(3))) unsigned int*)l,
                                     16, 0, 0);
}

// ---------------------------------------------------------------------------
// preprocessing: counts, inv, scan -> CSR grouped by (relation, dst)
// ---------------------------------------------------------------------------
__global__ __launch_bounds__(256) void count_edges(const int* __restrict__ dst,
                                                   const int* __restrict__ et,
                                                   int* __restrict__ cnt, int E) {
    int e = blockIdx.x * 256 + threadIdx.x;
    if (e < E) atomicAdd(&cnt[et[e] * N_NODES_C + dst[e]], 1);
}

__global__ __launch_bounds__(256) void make_inv(const int* __restrict__ cnt,
                                                float* __restrict__ inv, int n) {
    int i = blockIdx.x * 256 + threadIdx.x;
    if (i < n) inv[i] = 1.0f / (float)(cnt[i] > 1 ? cnt[i] : 1);
}

__global__ __launch_bounds__(256) void scan_block(const int* __restrict__ cnt,
                                                  int* __restrict__ rowptr,
                                                  int* __restrict__ bsum, int n) {
    __shared__ int sh[256];
    int tid = threadIdx.x;
    int i = blockIdx.x * 256 + tid;
    int v = (i < n) ? cnt[i] : 0;
    sh[tid] = v;
    __syncthreads();
#pragma unroll
    for (int o = 1; o < 256; o <<= 1) {
        int t = (tid >= o) ? sh[tid - o] : 0;
        __syncthreads();
        sh[tid] += t;
        __syncthreads();
    }
    if (i < n) rowptr[i] = sh[tid] - v;
    if (tid == 255) bsum[blockIdx.x] = sh[255];
}

__global__ __launch_bounds__(256) void scan_bsum(int* __restrict__ bsum, int nb) {
    __shared__ int sh[256];
    __shared__ int carry;
    int tid = threadIdx.x;
    if (tid == 0) carry = 0;
    __syncthreads();
    for (int base = 0; base < nb; base += 256) {
        int i = base + tid;
        int v = (i < nb) ? bsum[i] : 0;
        sh[tid] = v;
        __syncthreads();
#pragma unroll
        for (int o = 1; o < 256; o <<= 1) {
            int t = (tid >= o) ? sh[tid - o] : 0;
            __syncthreads();
            sh[tid] += t;
            __syncthreads();
        }
        int excl = sh[tid] - v + carry;
        int chunk_total = sh[255];
        __syncthreads();
        if (i < nb) bsum[i] = excl;
        if (tid == 0) carry += chunk_total;
        __syncthreads();
    }
}

// writes rowptr (final) AND cursor copy (folds the old 2MB memcpy)
__global__ __launch_bounds__(256) void scan_add(int* __restrict__ rowptr,
                                                const int* __restrict__ bsum,
                                                int* __restrict__ cursor,
                                                int n, int Etot) {
    int i = blockIdx.x * 256 + threadIdx.x;
    if (i < n) {
        int v = rowptr[i] + bsum[blockIdx.x];
        rowptr[i] = v;
        cursor[i] = v;
    }
    if (i == 0) rowptr[n] = Etot;
}

// ---------------------------------------------------------------------------
// bucket sort of edges by dst>>11 (64 buckets) to localize fill_csr writes
// ---------------------------------------------------------------------------
__global__ __launch_bounds__(256) void bucket_hist(const int* __restrict__ dst,
                                                   int* __restrict__ bhist, int E) {
    __shared__ int lh[NBUK];
    if (threadIdx.x < NBUK) lh[threadIdx.x] = 0;
    __syncthreads();
    for (int i = blockIdx.x * 256 + threadIdx.x; i < E; i += gridDim.x * 256)
        atomicAdd(&lh[dst[i] >> 11], 1);
    __syncthreads();
    if (threadIdx.x < NBUK && lh[threadIdx.x] > 0)
        atomicAdd(&bhist[threadIdx.x], lh[threadIdx.x]);
}

__global__ void bucket_scan(const int* __restrict__ bhist, int* __restrict__ bcursor) {
    if (threadIdx.x == 0) {
        int a = 0;
        for (int i = 0; i < NBUK; i++) { bcursor[i] = a; a += bhist[i]; }
    }
}

// scatter packed (src, dst|et<<20) into bucket order; per-block run reservation
__global__ __launch_bounds__(256) void bucket_scatter(const int* __restrict__ src,
                                                      const int* __restrict__ dst,
                                                      const int* __restrict__ et,
                                                      int* __restrict__ bcursor,
                                                      uint2* __restrict__ packed, int E) {
    __shared__ int lh[NBUK];
    __shared__ int lbase[NBUK];
    int tid = threadIdx.x;
    int e = blockIdx.x * 256 + tid;
    if (tid < NBUK) lh[tid] = 0;
    __syncthreads();
    int s = 0, key = 0, pay = 0, rank = 0;
    bool valid = (e < E);
    if (valid) {
        s = src[e];
        int d = dst[e], t = et[e];
        key = d >> 11;
        pay = d | (t << 20);
        rank = atomicAdd(&lh[key], 1);
    }
    __syncthreads();
    if (tid < NBUK && lh[tid] > 0) lbase[tid] = atomicAdd(&bcursor[tid], lh[tid]);
    __syncthreads();
    if (valid) packed[lbase[key] + rank] = (uint2){(unsigned)s, (unsigned)pay};
}

// fill in bucket order: cursor atomics + esrc writes hit small hot windows
__global__ __launch_bounds__(256) void fill_csr2(const uint2* __restrict__ packed,
                                                 int* __restrict__ cursor,
                                                 int* __restrict__ esrc, int E) {
    int e = blockIdx.x * 256 + threadIdx.x;
    if (e < E) {
        uint2 p = packed[e];
        int d = p.y & 0xFFFFF;
        int t = p.y >> 20;
        int pos = atomicAdd(&cursor[t * N_NODES_C + d], 1);
        esrc[pos] = p.x;
    }
}

// ---------------------------------------------------------------------------
// conversions to bf16
// ---------------------------------------------------------------------------
__global__ __launch_bounds__(256) void convert_x(const float* __restrict__ x,
                                                 unsigned short* __restrict__ xb, int n4) {
    int i = blockIdx.x * 256 + threadIdx.x;
    if (i >= n4) return;
    float4 v = ((const float4*)x)[i];
    ushort4 o;
    o.x = f2bf(v.x); o.y = f2bf(v.y); o.z = f2bf(v.z); o.w = f2bf(v.w);
    ((ushort4*)xb)[i] = o;
}

// Bt[c][kv] (col-major over virtual K): kv<128 -> root[kv][c]; else W[r][kk][c]
__global__ __launch_bounds__(256) void convert_w(const float* __restrict__ root,
                                                 const float* __restrict__ W,
                                                 unsigned short* __restrict__ Bt) {
    int idx = blockIdx.x * 256 + threadIdx.x;
    if (idx >= FEAT * KTOT) return;
    int c = idx / KTOT;
    int kv = idx - c * KTOT;
    float val;
    if (kv < FEAT) {
        val = root[kv * FEAT + c];
    } else {
        int r = (kv - FEAT) >> 7;
        int kk = (kv - FEAT) & 127;
        val = W[((size_t)r * FEAT + kk) * FEAT + c];
    }
    Bt[idx] = f2bf(val);
}

// ---------------------------------------------------------------------------
// gather: agg[r][local][:] = mean over CSR[r][node] of hb[src][:]  (bf16 out)
// quarter-wave (16 lanes) per (relation, node); lane = feat-seg (16B of row).
// agg stores nontemporal: write-once, consumed by next kernel from L3/HBM --
// keeps L2 free for the 16x-reused hb rows.
// ---------------------------------------------------------------------------
__global__ __launch_bounds__(256) void gather_mean(const unsigned short* __restrict__ hb,
                                                   const int* __restrict__ esrc,
                                                   const int* __restrict__ rowptr,
                                                   const float* __restrict__ inv,
                                                   unsigned short* __restrict__ agg,
                                                   int chunk0, int CL) {
    int qw = threadIdx.x >> 4;       // 0..15 quarter-waves per block
    int seg = threadIdx.x & 15;      // feats [seg*8, seg*8+8)
    int local = blockIdx.x * 16 + qw;
    if (local >= CL) return;
    int r = blockIdx.y;
    int node = chunk0 + local;
    int lo = rowptr[r * N_NODES_C + node];
    int hi = rowptr[r * N_NODES_C + node + 1];

    float acc[8];
#pragma unroll
    for (int j = 0; j < 8; j++) acc[j] = 0.f;

    for (int e = lo; e < hi; e++) {
        int s = esrc[e];
        uint4 u = *(const uint4*)(hb + ((size_t)s << 7) + seg * 8);
        union { unsigned int u; float f; } t;
        t.u = u.x << 16;         acc[0] += t.f;
        t.u = u.x & 0xFFFF0000u; acc[1] += t.f;
        t.u = u.y << 16;         acc[2] += t.f;
        t.u = u.y & 0xFFFF0000u; acc[3] += t.f;
        t.u = u.z << 16;         acc[4] += t.f;
        t.u = u.z & 0xFFFF0000u; acc[5] += t.f;
        t.u = u.w << 16;         acc[6] += t.f;
        t.u = u.w & 0xFFFF0000u; acc[7] += t.f;
    }
    float sc = inv[r * N_NODES_C + node];
    u32x4 o;
    o.x = ((unsigned int)f2bf(acc[1] * sc) << 16) | f2bf(acc[0] * sc);
    o.y = ((unsigned int)f2bf(acc[3] * sc) << 16) | f2bf(acc[2] * sc);
    o.z = ((unsigned int)f2bf(acc[5] * sc) << 16) | f2bf(acc[4] * sc);
    o.w = ((unsigned int)f2bf(acc[7] * sc) << 16) | f2bf(acc[6] * sc);
    __builtin_nontemporal_store(o, (u32x4*)(agg + (((size_t)r * CL + local) << 7) + seg * 8));
}

// ---------------------------------------------------------------------------
// MFMA GEMM (m97-style): C[n][0:128] = relu( A_virt[n][0:768] @ B + bias )
//   A_virt k<128 -> hb[node][k]; k>=128 -> agg[r][local][k%128] (pre-scaled means)
// BK=64, global_load_lds(16B) staging, chunk-XOR swizzled unpadded LDS.
// Block 128x128, 4 waves 2x2, wave tile 64x64 (4x4 MFMA 16x16x32 tiles).
// ---------------------------------------------------------------------------
__global__ __launch_bounds__(256) void rgcn_gemm(const unsigned short* __restrict__ hb,
                                                 const unsigned short* __restrict__ agg,
                                                 const unsigned short* __restrict__ Bt,
                                                 const float* __restrict__ bias,
                                                 float* __restrict__ outf,
                                                 unsigned short* __restrict__ outb,
                                                 int chunk0, int CL) {
    __shared__ unsigned short As[BM * GBK];    // 16 KB
    __shared__ unsigned short Bs[FEAT * GBK];  // 16 KB

    const int tid = threadIdx.x;
    const int w = tid >> 6, lane = tid & 63;
    const int wr = w >> 1, wc = w & 1;
    const int lm = lane & 15, lq = lane >> 4;
    const int brow0 = blockIdx.x * BM;

    f32x4 acc[4][4];
#pragma unroll
    for (int i = 0; i < 4; i++)
#pragma unroll
        for (int j = 0; j < 4; j++) acc[i][j] = (f32x4){0.f, 0.f, 0.f, 0.f};

    size_t hboff[4];
    size_t aggoff[4];
    size_t boff[4];
    int ldsbase[4];
#pragma unroll
    for (int i = 0; i < 4; i++) {
        int cid = (w * 4 + i) * 64 + lane;
        int row = cid >> 3;
        int cs = (cid & 7) ^ (row & 7);
        int gr = brow0 + row;
        if (gr >= CL) gr = CL - 1;
        hboff[i]  = ((size_t)(chunk0 + gr) << 7) + cs * 8;
        aggoff[i] = ((size_t)gr << 7) + cs * 8;
        boff[i]   = (size_t)row * KTOT + cs * 8;
        ldsbase[i] = ((w * 4 + i) * 64) * 8;
    }

    for (int kb = 0; kb < KTOT; kb += GBK) {
        __syncthreads();
        if (kb < FEAT) {
#pragma unroll
            for (int i = 0; i < 4; i++)
                g2l16(hb + hboff[i] + kb, &As[ldsbase[i]]);
        } else {
            size_t reloff = (((size_t)((kb - FEAT) >> 7)) * CL << 7) + (size_t)((kb - FEAT) & 127);
#pragma unroll
            for (int i = 0; i < 4; i++)
                g2l16(agg + aggoff[i] + reloff, &As[ldsbase[i]]);
        }
#pragma unroll
        for (int i = 0; i < 4; i++)
            g2l16(Bt + boff[i] + kb, &Bs[ldsbase[i]]);
        __syncthreads();

#pragma unroll
        for (int h = 0; h < 2; h++) {
            bf16x8 af[4], bf[4];
#pragma unroll
            for (int t = 0; t < 4; t++) {
                int row = wr * 64 + t * 16 + lm;
                int ca = (h * 4 + lq) ^ (row & 7);
                af[t] = *(const bf16x8*)&As[row * GBK + ca * 8];
                int col = wc * 64 + t * 16 + lm;
                int cb = (h * 4 + lq) ^ (col & 7);
                bf[t] = *(const bf16x8*)&Bs[col * GBK + cb * 8];
            }
#pragma unroll
            for (int i = 0; i < 4; i++)
#pragma unroll
                for (int j = 0; j < 4; j++)
                    acc[i][j] = __builtin_amdgcn_mfma_f32_16x16x32_bf16(af[i], bf[j], acc[i][j], 0, 0, 0);
        }
    }

    float bcol[4];
#pragma unroll
    for (int j = 0; j < 4; j++) bcol[j] = bias[wc * 64 + j * 16 + lm];

#pragma unroll
    for (int i = 0; i < 4; i++) {
#pragma unroll
        for (int reg = 0; reg < 4; reg++) {
            int lr = brow0 + wr * 64 + i * 16 + lq * 4 + reg;
            if (lr < CL) {
                size_t grow = (size_t)(chunk0 + lr) << 7;
#pragma unroll
                for (int j = 0; j < 4; j++) {
                    float v = acc[i][j][reg] + bcol[j];
                    v = fmaxf(v, 0.f);
                    int col = wc * 64 + j * 16 + lm;
                    if (outf) outf[grow + col] = v;
                    else outb[grow + col] = f2bf(v);
                }
            }
        }
    }
}

// ---------------------------------------------------------------------------
extern "C" void kernel_launch(void* const* d_in, const int* in_sizes, int n_in,
                              void* d_out, int out_size, void* d_ws, size_t ws_size,
                              hipStream_t stream) {
    const float* x = (const float*)d_in[0];
    const int* ei  = (const int*)d_in[1];
    const int* et  = (const int*)d_in[2];
    const int E = in_sizes[2];
    const int* src  = ei;
    const int* dstp = ei + E;

    // workspace layout:
    //   inv    @ 0           (2,000,000)
    //   rowptr @ 2,097,152   (2,000,004)
    //   esrc   @ 4,194,304   (6,400,000)
    //   xbA    @ 10,616,832  (25,600,000)
    //   xbB    @ 36,306,944  (25,600,000)
    //   agg    @ 61,997,056  (CL*1280)      [preproc scratch aliases below]
    //     cnt    @ agg+0        (2,000,000)
    //     cursor @ agg+2MiB     (2,000,000)
    //     bsum   @ agg+4MiB     (~8 KB)
    //     bhist  @ agg+4MiB+16K (256 B)
    //     bcur   @ agg+4MiB+17K (256 B)
    //     packed @ agg+8MiB     (12,800,000)   [all dead before first gather]
    //   Bt     @ agg + CL*1280  (589,824)
    // CL from ws_size (CL=100000 path proven rounds 4-6: 190.6 MB).
    int CL = 25000;
    if (ws_size >= 61997056ull + 100000ull * 1280ull + 589824ull) CL = 100000;
    else if (ws_size >= 61997056ull + 50000ull * 1280ull + 589824ull) CL = 50000;
    const int NCHUNK = N_NODES_C / CL;

    char* ws = (char*)d_ws;
    float* inv             = (float*)ws;
    int*   rowptr          = (int*)(ws + 2097152);
    int*   esrc            = (int*)(ws + 4194304);
    unsigned short* xbA    = (unsigned short*)(ws + 10616832);
    unsigned short* xbB    = (unsigned short*)(ws + 36306944);
    unsigned short* agg    = (unsigned short*)(ws + 61997056);
    unsigned short* BtAll  = (unsigned short*)(ws + 61997056 + (size_t)CL * 1280ull);
    int*   cnt     = (int*)(ws + 61997056);
    int*   cursor  = (int*)(ws + 61997056 + 2097152);
    int*   bsum    = (int*)(ws + 61997056 + 4194304);
    int*   bhist   = (int*)(ws + 61997056 + 4194304 + 16384);
    int*   bcursor = (int*)(ws + 61997056 + 4194304 + 17408);
    uint2* packed  = (uint2*)(ws + 61997056 + 8388608);

    const int nscan_blocks = (N_TOT + 255) / 256;
    const int egrid = (E + 255) / 256;

    hipMemsetAsync(cnt, 0, (size_t)N_TOT * 4, stream);
    hipMemsetAsync(bhist, 0, NBUK * 4, stream);
    count_edges<<<egrid, 256, 0, stream>>>(dstp, et, cnt, E);
    make_inv<<<(N_TOT + 255) / 256, 256, 0, stream>>>(cnt, inv, N_TOT);
    scan_block<<<nscan_blocks, 256, 0, stream>>>(cnt, rowptr, bsum, N_TOT);
    scan_bsum<<<1, 256, 0, stream>>>(bsum, nscan_blocks);
    scan_add<<<nscan_blocks, 256, 0, stream>>>(rowptr, bsum, cursor, N_TOT, E);
    bucket_hist<<<512, 256, 0, stream>>>(dstp, bhist, E);
    bucket_scan<<<1, 64, 0, stream>>>(bhist, bcursor);
    bucket_scatter<<<egrid, 256, 0, stream>>>(src, dstp, et, bcursor, packed, E);
    fill_csr2<<<egrid, 256, 0, stream>>>(packed, cursor, esrc, E);

    const int n4 = N_NODES_C * FEAT / 4;
    convert_x<<<(n4 + 255) / 256, 256, 0, stream>>>(x, xbA, n4);

    const float* Wp[3] = {(const float*)d_in[3], (const float*)d_in[6], (const float*)d_in[9]};
    const float* Rp[3] = {(const float*)d_in[4], (const float*)d_in[7], (const float*)d_in[10]};
    const float* Bp[3] = {(const float*)d_in[5], (const float*)d_in[8], (const float*)d_in[11]};

    const int nw = FEAT * KTOT;
    for (int l = 0; l < 3; l++)
        convert_w<<<(nw + 255) / 256, 256, 0, stream>>>(Rp[l], Wp[l],
                                                        BtAll + (size_t)l * nw);

    const int gemm_grid = (CL + BM - 1) / BM;
    dim3 ggrid((CL + 15) / 16, N_REL_C);

    // layer dataflow (bf16 ping-pong): xbA -> xbB -> xbA -> d_out(fp32)
    for (int l = 0; l < 3; l++) {
        const unsigned short* hin = (l == 1) ? xbB : xbA;
        unsigned short* outb = (l == 0) ? xbB : ((l == 1) ? xbA : nullptr);
        float* outf = (l == 2) ? (float*)d_out : nullptr;
        for (int c = 0; c < NCHUNK; c++) {
            gather_mean<<<ggrid, 256, 0, stream>>>(hin, esrc, rowptr, inv, agg,
                                                   c * CL, CL);
            rgcn_gemm<<<gemm_grid, 256, 0, stream>>>(hin, agg, BtAll + (size_t)l * nw,
                                                     Bp[l], outf, outb, c * CL, CL);
        }
    }
}